// Round 2
// baseline (972.020 us; speedup 1.0000x reference)
//
#include <hip/hip_runtime.h>
#include <hip/hip_bf16.h>
#include <stdint.h>

typedef __bf16 bf16;
typedef bf16 bf16x8 __attribute__((ext_vector_type(8)));
typedef float f32x4 __attribute__((ext_vector_type(4)));

#define D 128

// ---------------- prep: swizzled V1 chunks + W1t + zero buffers + compact edges ----------------
// V1p layout: 2 chunks of 192 cols. chunk c, local col nl (0..191), k (0..383):
//   byte off = c*147456 + ((nl*768 + k*2) ^ ((nl&7)<<4))
// XOR touches bits 4-6 only -> stays within the row's 128B block; makes the GEMM's
// stride-768 ds_read_b128 column reads conflict-free (8-way spread, 2-way residual = free).
__global__ void prep_compact_kernel(const float* __restrict__ V1, const float* __restrict__ W1,
                                    bf16* __restrict__ V1p, bf16* __restrict__ W1t,
                                    const int* __restrict__ ei, int E, int bs,
                                    int* __restrict__ count, int* __restrict__ list,
                                    float* __restrict__ signal, float* __restrict__ score) {
  int i = blockIdx.x * 256 + threadIdx.x;
  if (i < 384 * 384) {
    int k = i / 384, n = i % 384;
    int c = (n >= 192) ? 1 : 0;
    int nl = n - c * 192;
    int off = c * 147456 + ((nl * 768 + k * 2) ^ ((nl & 7) << 4));
    *(bf16*)((char*)V1p + off) = (bf16)V1[i];
  }
  if (i < 128 * 128) { int k = i >> 7, n = i & 127;  W1t[n * 128 + k] = (bf16)W1[i]; }
  if (i < bs) signal[i] = 0.f;
  if (i < E + 64) score[i] = 0.f;
  if (i < E && ei[i] < bs) {
    int p = atomicAdd(count, 1);   // wave-aggregated by compiler
    list[p] = i;
  }
}

// ---------------- node MLP: logits = relu(x@W1+b1)@W2 + b2 (unchanged) ----------------
__global__ __launch_bounds__(256, 2) void node_kernel(
    const float* __restrict__ x, const bf16* __restrict__ W1t,
    const float* __restrict__ b1, const float* __restrict__ W2,
    const float* __restrict__ b2, float* __restrict__ logits, int bs)
{
  __shared__ bf16 sA[64][136];
  __shared__ float sOut0[64], sOut1[64];

  int tid = threadIdx.x;
  if (tid < 64) { sOut0[tid] = 0.f; sOut1[tid] = 0.f; }

  {
    int g = tid >> 5, fl = tid & 31;
#pragma unroll
    for (int i = 0; i < 8; ++i) {
      int row = i * 8 + g;
      const float4* base = (const float4*)(x + (size_t)(blockIdx.x * 64 + row) * D);
      float4 v = base[fl];
      union { bf16 h[4]; uint2 u; } cv;
      cv.h[0] = (bf16)v.x; cv.h[1] = (bf16)v.y; cv.h[2] = (bf16)v.z; cv.h[3] = (bf16)v.w;
      *(uint2*)&sA[row][fl * 4] = cv.u;
    }
  }
  __syncthreads();

  int wave = tid >> 6, lane = tid & 63;
  int l15 = lane & 15, quad = lane >> 4;

  f32x4 acc[2][4];
#pragma unroll
  for (int ct = 0; ct < 2; ++ct)
#pragma unroll
    for (int rt = 0; rt < 4; ++rt)
      acc[ct][rt] = (f32x4){0.f, 0.f, 0.f, 0.f};

  for (int kc = 0; kc < 4; ++kc) {
    int k = kc * 32 + quad * 8;
    bf16x8 a[4], b[2];
#pragma unroll
    for (int rt = 0; rt < 4; ++rt)
      a[rt] = *(const bf16x8*)&sA[rt * 16 + l15][k];
#pragma unroll
    for (int ct = 0; ct < 2; ++ct)
      b[ct] = *(const bf16x8*)&W1t[(size_t)(wave * 32 + ct * 16 + l15) * 128 + k];
#pragma unroll
    for (int ct = 0; ct < 2; ++ct)
#pragma unroll
      for (int rt = 0; rt < 4; ++rt)
        acc[ct][rt] = __builtin_amdgcn_mfma_f32_16x16x32_bf16(a[rt], b[ct], acc[ct][rt], 0, 0, 0);
  }

  float bc[2], w0[2], w1[2];
#pragma unroll
  for (int ct = 0; ct < 2; ++ct) {
    int n = wave * 32 + ct * 16 + l15;
    bc[ct] = b1[n]; w0[ct] = W2[n * 2]; w1[ct] = W2[n * 2 + 1];
  }
#pragma unroll
  for (int rt = 0; rt < 4; ++rt) {
#pragma unroll
    for (int reg = 0; reg < 4; ++reg) {
      float p0 = 0.f, p1 = 0.f;
#pragma unroll
      for (int ct = 0; ct < 2; ++ct) {
        float h = fmaxf(acc[ct][rt][reg] + bc[ct], 0.f);
        p0 += h * w0[ct]; p1 += h * w1[ct];
      }
      p0 += __shfl_xor(p0, 1, 16); p0 += __shfl_xor(p0, 2, 16);
      p0 += __shfl_xor(p0, 4, 16); p0 += __shfl_xor(p0, 8, 16);
      p1 += __shfl_xor(p1, 1, 16); p1 += __shfl_xor(p1, 2, 16);
      p1 += __shfl_xor(p1, 4, 16); p1 += __shfl_xor(p1, 8, 16);
      if (l15 == 0) {
        int row = rt * 16 + quad * 4 + reg;
        atomicAdd(&sOut0[row], p0);
        atomicAdd(&sOut1[row], p1);
      }
    }
  }
  __syncthreads();
  if (tid < 64) {
    int node = blockIdx.x * 64 + tid;
    if (node < bs) {
      logits[2 * node]     = sOut0[tid] + b2[0];
      logits[2 * node + 1] = sOut1[tid] + b2[1];
    }
  }
}

// ---------------- edge GEMM: stationary-B in LDS, direct-gather A, persistent waves ----------
// Grid = 256 blocks x 512 threads (1 block/CU, 8 waves). chunk = blockIdx&1 (192 N-cols).
// Block loads its 144KB B chunk once, one barrier, then waves independently grid-stride
// over (tile, row-half) units: 32 edge rows x 192 cols, K=384. A fragments are gathered
// DIRECTLY from x/ea (per-lane rows -> fragment layout is natively gatherable).
// Partial scores (relu(h)@V2 over this chunk's cols) atomicAdd into global score[].
__global__ __launch_bounds__(512, 2) void edge_gemm_kernel(
    const float* __restrict__ x, const float* __restrict__ ea,
    const bf16* __restrict__ V1p, const float* __restrict__ bv1,
    const float* __restrict__ V2, const int* __restrict__ ei,
    const int* __restrict__ count, const int* __restrict__ list,
    float* __restrict__ score, int E)
{
  __shared__ __align__(16) char sB[147456];   // 192 rows x 384 k bf16, XOR-swizzled

  int tid = threadIdx.x;
  int wave = tid >> 6, lane = tid & 63;
  int l15 = lane & 15, quad = lane >> 4;
  int chunk = blockIdx.x & 1;

  // stage B chunk: 18 rounds x (8 waves x 64 lanes x 16B) = 147456 B, linear copy
  const char* bsrc = (const char*)V1p + (size_t)chunk * 147456;
#pragma unroll
  for (int i = 0; i < 18; ++i) {
    int off = i * 8192 + wave * 1024;        // wave-uniform LDS base; HW adds lane*16
    __builtin_amdgcn_global_load_lds(
        (const __attribute__((address_space(1))) unsigned int*)(bsrc + off + lane * 16),
        (__attribute__((address_space(3))) unsigned int*)(sB + off),
        16, 0, 0);
  }

  int cnt = *count;

  float bvc[12], v2c[12];
#pragma unroll
  for (int ct = 0; ct < 12; ++ct) {
    int n = chunk * 192 + ct * 16 + l15;
    bvc[ct] = bv1[n]; v2c[ct] = V2[n];
  }

  asm volatile("s_waitcnt vmcnt(0)" ::: "memory");
  __syncthreads();
  // no barriers after this point: waves are independent

  int ntiles = (cnt + 63) >> 6;
  int nunits = ntiles * 2;
  int worker = (int)(blockIdx.x >> 1) * 8 + wave;   // 0..1023 per chunk
  int xr = (l15 & 7) << 4;

  for (int u = worker; u < nunits; u += 1024) {
    int tile = u >> 1, half = u & 1;
    int rowbase = tile * 64 + half * 32;

    // per-lane gather rows (A fragment rows are indexed by l15)
    int pr0 = rowbase + l15;
    int pr1 = pr0 + 16;
    int e0 = (pr0 < cnt) ? list[pr0] : 0;
    int e1 = (pr1 < cnt) ? list[pr1] : 0;
    int s0 = ei[e0], d0 = ei[E + e0];
    int s1 = ei[e1], d1 = ei[E + e1];
    const float* xs0 = x + (size_t)s0 * D;
    const float* xd0 = x + (size_t)d0 * D;
    const float* pe0 = ea + (size_t)e0 * D;
    const float* xs1 = x + (size_t)s1 * D;
    const float* xd1 = x + (size_t)d1 * D;
    const float* pe1 = ea + (size_t)e1 * D;

    f32x4 acc[12][2];
#pragma unroll
    for (int ct = 0; ct < 12; ++ct) {
      acc[ct][0] = (f32x4){0.f, 0.f, 0.f, 0.f};
      acc[ct][1] = (f32x4){0.f, 0.f, 0.f, 0.f};
    }

#pragma unroll
    for (int kc = 0; kc < 12; ++kc) {
      const int seg = kc >> 2;               // 0:x[src] 1:x[dst] 2:ea[e]  (compile-time)
      int kf = (kc & 3) * 32 + quad * 8;     // float offset within segment
      const float* base0 = (seg == 0) ? xs0 : (seg == 1) ? xd0 : pe0;
      const float* base1 = (seg == 0) ? xs1 : (seg == 1) ? xd1 : pe1;

      float4 v0a = *(const float4*)(base0 + kf);
      float4 v0b = *(const float4*)(base0 + kf + 4);
      float4 v1a = *(const float4*)(base1 + kf);
      float4 v1b = *(const float4*)(base1 + kf + 4);

      union { bf16 h[8]; bf16x8 v; } ca, cb;
      ca.h[0] = (bf16)v0a.x; ca.h[1] = (bf16)v0a.y; ca.h[2] = (bf16)v0a.z; ca.h[3] = (bf16)v0a.w;
      ca.h[4] = (bf16)v0b.x; ca.h[5] = (bf16)v0b.y; ca.h[6] = (bf16)v0b.z; ca.h[7] = (bf16)v0b.w;
      cb.h[0] = (bf16)v1a.x; cb.h[1] = (bf16)v1a.y; cb.h[2] = (bf16)v1a.z; cb.h[3] = (bf16)v1a.w;
      cb.h[4] = (bf16)v1b.x; cb.h[5] = (bf16)v1b.y; cb.h[6] = (bf16)v1b.z; cb.h[7] = (bf16)v1b.w;
      bf16x8 a0 = ca.v, a1 = cb.v;

      bf16x8 b[12];
#pragma unroll
      for (int ct = 0; ct < 12; ++ct) {
        int off = ((ct * 16 + l15) * 768 + kc * 64 + quad * 16) ^ xr;
        b[ct] = *(const bf16x8*)(sB + off);
      }
#pragma unroll
      for (int ct = 0; ct < 12; ++ct) {
        acc[ct][0] = __builtin_amdgcn_mfma_f32_16x16x32_bf16(a0, b[ct], acc[ct][0], 0, 0, 0);
        acc[ct][1] = __builtin_amdgcn_mfma_f32_16x16x32_bf16(a1, b[ct], acc[ct][1], 0, 0, 0);
      }
    }

    // epilogue: +bv1, relu, dot V2 (this chunk's 192 cols), reduce over l15, global add
#pragma unroll
    for (int rt = 0; rt < 2; ++rt) {
#pragma unroll
      for (int reg = 0; reg < 4; ++reg) {
        float p = 0.f;
#pragma unroll
        for (int ct = 0; ct < 12; ++ct)
          p += fmaxf(acc[ct][rt][reg] + bvc[ct], 0.f) * v2c[ct];
        p += __shfl_xor(p, 1, 16);
        p += __shfl_xor(p, 2, 16);
        p += __shfl_xor(p, 4, 16);
        p += __shfl_xor(p, 8, 16);
        if (l15 == 0)
          atomicAdd(&score[rowbase + rt * 16 + quad * 4 + reg], p);
      }
    }
  }
}

// ---------------- finalize: sigmoid + segment-max into signal ----------------
__global__ void finalize_kernel(const float* __restrict__ score, const int* __restrict__ count,
                                const int* __restrict__ list, const int* __restrict__ ei,
                                const float* __restrict__ bv2, float* __restrict__ signal) {
  int p = blockIdx.x * 256 + threadIdx.x;
  if (p < *count) {
    float sc = score[p] + bv2[0];
    float sig = 1.f / (1.f + __expf(-sc));
    // sigmoid > 0, signal init 0: positive-float int compare == float max
    atomicMax((int*)&signal[ei[list[p]]], __float_as_int(sig));
  }
}

// ---------------- combine + labels ----------------
__global__ void combine_kernel(const float* __restrict__ logits, const float* __restrict__ signal,
                               const int* __restrict__ y, const float* __restrict__ ecw,
                               float* __restrict__ out, int bs) {
  int i = blockIdx.x * 256 + threadIdx.x;
  if (i < bs) {
    out[2 * i]     = logits[2 * i];
    out[2 * i + 1] = logits[2 * i + 1] + ecw[0] * signal[i];
    out[2 * bs + i] = (float)y[i];
  }
}

extern "C" void kernel_launch(void* const* d_in, const int* in_sizes, int n_in,
                              void* d_out, int out_size, void* d_ws, size_t ws_size,
                              hipStream_t stream) {
  const float* x   = (const float*)d_in[0];
  const float* ea  = (const float*)d_in[1];
  const float* W1  = (const float*)d_in[2];
  const float* b1  = (const float*)d_in[3];
  const float* W2  = (const float*)d_in[4];
  const float* b2  = (const float*)d_in[5];
  const float* V1  = (const float*)d_in[6];
  const float* bv1 = (const float*)d_in[7];
  const float* V2  = (const float*)d_in[8];
  const float* bv2 = (const float*)d_in[9];
  const float* ecw = (const float*)d_in[10];
  const int*   ei  = (const int*)d_in[11];
  const int*   y   = (const int*)d_in[12];

  int E  = in_sizes[1] / D;
  int bs = out_size / 3;

  char* ws = (char*)d_ws;
  size_t off = 0;
  auto rnd16 = [](size_t v) { return (v + 15) & ~(size_t)15; };
  bf16* V1p = (bf16*)(ws + off); off += (size_t)2 * 147456;        // swizzled chunks
  bf16* W1t = (bf16*)(ws + off); off += (size_t)128 * 128 * 2;
  float* signal = (float*)(ws + off); off += rnd16((size_t)bs * 4);
  float* logits = (float*)(ws + off); off += rnd16((size_t)bs * 8);
  int* count = (int*)(ws + off); off += 16;
  int* list  = (int*)(ws + off); off += rnd16((size_t)E * 4);
  float* score = (float*)(ws + off); off += rnd16((size_t)(E + 64) * 4);

  hipMemsetAsync(count, 0, 4, stream);

  int maxi = E + 64;
  if (384 * 384 > maxi) maxi = 384 * 384;
  if (bs > maxi) maxi = bs;
  prep_compact_kernel<<<(maxi + 255) / 256, 256, 0, stream>>>(
      V1, W1, V1p, W1t, ei, E, bs, count, list, signal, score);

  edge_gemm_kernel<<<256, 512, 0, stream>>>(x, ea, V1p, bv1, V2,
                                            ei, count, list, score, E);
  node_kernel<<<(bs + 63) / 64, 256, 0, stream>>>(x, W1t, b1, W2, b2, logits, bs);
  finalize_kernel<<<(E + 255) / 256, 256, 0, stream>>>(score, count, list, ei, bv2, signal);
  combine_kernel<<<(bs + 255) / 256, 256, 0, stream>>>(logits, signal, y, ecw,
                                                       (float*)d_out, bs);
}